// Round 13
// baseline (240.671 us; speedup 1.0000x reference)
//
#include <hip/hip_runtime.h>
#include <stdint.h>
#include <math.h>

typedef unsigned short u16;
typedef unsigned int u32;
typedef unsigned long long u64;

#define NBW 120
#define NBH 68
#define NTILES (NBW * NBH)       // 8160
#define NPTS 500000
#define EE 12500000              // N * K * K
#define SORT_CAP 1024            // max tile count ~545 expected; global fallback guards
#define NBKT 512                 // distribution-sort buckets
#define HB 64                    // hist/scatter blocks
#define HT 1024                  // hist/scatter threads per block
#define DX 121                   // diff array x dim (0..120)
#define DY 69                    // diff array y dim (0..68)
#define DCELLS 8352              // 121*69 = 8349, padded even
#define DCW (DCELLS / 2)         // packed i16 words per slice = 4176
#define PCW 4080                 // 8160 cells / 2 per u16-packed word

__device__ __forceinline__ int clampi(int v, int lo, int hi) {
    return v < lo ? lo : (v > hi ? hi : v);
}

__device__ __forceinline__ void tile_window(float x, float y, float r,
                                            int& x0, int& x1, int& y0, int& y1) {
    x0 = clampi((int)floorf((x - r) * 0.0625f), 0, NBW);
    x1 = clampi((int)floorf((x + r) * 0.0625f) + 1, 0, NBW);
    y0 = clampi((int)floorf((y - r) * 0.0625f), 0, NBH);
    y1 = clampi((int)floorf((y + r) * 0.0625f) + 1, 0, NBH);
}

// monotone float -> u32 such that ascending u32 == DESCENDING float
__device__ __forceinline__ u32 depth_key(float d) {
    u32 fu = __float_as_uint(d);
    u32 asc = (fu & 0x80000000u) ? ~fu : (fu | 0x80000000u);
    return ~asc;
}
__device__ __forceinline__ float depth_unkey(u32 dk) {
    u32 asc = ~dk;
    u32 fu = (asc & 0x80000000u) ? (asc & 0x7FFFFFFFu) : ~asc;
    return __uint_as_float(fu);
}

__device__ __forceinline__ int tile_of_block(int b) {
    return (b & 7) * (NTILES / 8) + (b >> 3);
}

// Exactly monotone (in dk) bucket map: table lookup on top-8 bits + integer
// linear interpolation. T is monotone non-decreasing, 0..NBKT.
__device__ __forceinline__ u32 bucket_of(u32 dk, const u32* __restrict__ Ts) {
    u32 k = dk >> 24;
    u32 t0 = Ts[k], t1 = Ts[k + 1];
    u32 b = t0 + (((t1 - t0) * ((dk >> 8) & 0xFFFFu)) >> 16);
    return b >= NBKT ? (NBKT - 1) : b;
}

__device__ __forceinline__ void lds_inc16(u32* arr, int cell) {
    atomicAdd(&arr[cell >> 1], (cell & 1) ? 0x10000u : 1u);
}

// 8-byte record: [dk:32 | pid:19 | dx0:2 | dx1m1:2 | y0:7 | h:2]
// Full u64 compare sorts by (dk, pid). Window relative-x fits because
// radius < 24 => window within center±2 and span <= 4.

// 64 blocks x 1024: LDS point-count histogram (packed u16) and LDS 2D
// difference-array corners (packed u16, plus/minus split -> i16 slices).
__global__ __launch_bounds__(HT) void hist_kernel(const float2* __restrict__ pos,
                                                  const float* __restrict__ rad,
                                                  u32* __restrict__ pcslc,
                                                  u32* __restrict__ diffslc) {
    __shared__ u32 s_pc[PCW];
    __shared__ u32 s_dp[DCW];
    __shared__ u32 s_dm[DCW];
    int tid = threadIdx.x;
    for (int w = tid; w < PCW; w += HT) s_pc[w] = 0;
    for (int w = tid; w < DCW; w += HT) { s_dp[w] = 0; s_dm[w] = 0; }
    __syncthreads();

    for (int i = blockIdx.x * HT + tid; i < NPTS; i += HB * HT) {
        float2 p = pos[i];
        float r = rad[i];
        int x0, x1, y0, y1;
        tile_window(p.x, p.y, r, x0, x1, y0, y1);
        int cx = (int)(p.x * 0.0625f);
        int cy = (int)(p.y * 0.0625f);
        lds_inc16(s_pc, cx * NBH + cy);
        lds_inc16(s_dp, x0 * DY + y0);
        lds_inc16(s_dp, x1 * DY + y1);
        lds_inc16(s_dm, x0 * DY + y1);
        lds_inc16(s_dm, x1 * DY + y0);
    }
    __syncthreads();

    for (int w = tid; w < PCW; w += HT) pcslc[blockIdx.x * PCW + w] = s_pc[w];
    for (int wi = tid; wi < DCW; wi += HT) {
        u32 pw = s_dp[wi], mw = s_dm[wi];
        int d0 = (int)(pw & 0xFFFFu) - (int)(mw & 0xFFFFu);
        int d1 = (int)(pw >> 16)     - (int)(mw >> 16);
        diffslc[blockIdx.x * DCW + wi] = ((u32)d0 & 0xFFFFu) | ((u32)d1 << 16);
    }
}

// One dispatch, 11 blocks: reduce + all scans.
//  block 0: sum pcslc columns (packed-u32 adds; halves can't carry since
//           per-tile total <= ~120) -> counts -> exclusive scan -> po
//  block 1: sum diffslc halves (sign-extended, FULL DCW coverage) -> sd[]
//           -> 2D prefix -> entry counts -> exclusive scan -> eo + out_count
//  block 2: bucket table -> Tg
//  blocks 3..10: u16 ctab0 cursor table (1 tile/thread, 64-slice prefix)
__global__ __launch_bounds__(1024) void scan_all_kernel(const u32* __restrict__ pcslc,
                                                        const u32* __restrict__ diffslc,
                                                        u32* __restrict__ po,
                                                        u32* __restrict__ eo,
                                                        float* __restrict__ out_count,
                                                        u32* __restrict__ Tg,
                                                        u16* __restrict__ ctab0) {
    __shared__ int sd[DCELLS];
    __shared__ u32 sA[1024], sB[1024];
    __shared__ u32 traw[257];
    int t = threadIdx.x;
    int b = blockIdx.x;
    int base = t * 8;

    if (b == 0) {
        // ---- packed column sum -> counts (registers) -> scan -> po ----
        u32 local[8];
        u32 sum = 0;
#pragma unroll
        for (int wj = 0; wj < 4; ++wj) {
            int w = t * 4 + wj;
            u32 ws = 0;
            if (w < PCW)
                for (int s = 0; s < HB; ++s) ws += pcslc[s * PCW + w];
            local[wj * 2]     = ws & 0xFFFFu;
            local[wj * 2 + 1] = ws >> 16;
            sum += (ws & 0xFFFFu) + (ws >> 16);
        }
        sA[t] = sum;
        __syncthreads();
        u32 *cur = sA, *nxt = sB;
        for (int off = 1; off < 1024; off <<= 1) {
            u32 v = cur[t];
            if (t >= off) v += cur[t - off];
            nxt[t] = v;
            __syncthreads();
            u32* tmp = cur; cur = nxt; nxt = tmp;
        }
        u32 run = cur[t] - sum;
#pragma unroll
        for (int j = 0; j < 8; ++j) {
            int idx = base + j;
            if (idx < NTILES) { po[idx] = run; run += local[j]; }
        }
        if (t == 1023) po[NTILES] = cur[1023];
    } else if (b == 1) {
        // ---- diff column sum (stride loop covers ALL DCW words) -> sd ----
        for (int wi = t; wi < DCW; wi += 1024) {
            int a0 = 0, a1 = 0;
            for (int s = 0; s < HB; ++s) {
                u32 v = diffslc[s * DCW + wi];
                a0 += (int)(short)(v & 0xFFFFu);
                a1 += (int)(short)(v >> 16);
            }
            sd[wi * 2] = a0;
            sd[wi * 2 + 1] = a1;
        }
        __syncthreads();
        if (t < DX) { int run = 0; for (int y = 0; y < DY; ++y) { run += sd[t * DY + y]; sd[t * DY + y] = run; } }
        __syncthreads();
        if (t < DY) { int run = 0; for (int x = 0; x < DX; ++x) { run += sd[x * DY + t]; sd[x * DY + t] = run; } }
        __syncthreads();

        u32 local[8]; u32 sum = 0;
#pragma unroll
        for (int j = 0; j < 8; ++j) {
            int idx = base + j;
            u32 c = 0;
            if (idx < NTILES) {
                int x = idx / NBH, y = idx % NBH;
                c = (u32)sd[x * DY + y];
            }
            local[j] = c; sum += c;
        }
        sA[t] = sum;
        __syncthreads();
        u32 *cur = sA, *nxt = sB;
        for (int off = 1; off < 1024; off <<= 1) {
            u32 v = cur[t];
            if (t >= off) v += cur[t - off];
            nxt[t] = v;
            __syncthreads();
            u32* tmp = cur; cur = nxt; nxt = tmp;
        }
        u32 run = cur[t] - sum;
#pragma unroll
        for (int j = 0; j < 8; ++j) {
            int idx = base + j;
            if (idx < NTILES) {
                eo[idx] = run;
                out_count[idx] = (float)run;
                run += local[j];
            }
        }
        if (t == 1023) eo[NTILES] = cur[1023];
    } else if (b == 2) {
        // ---- bucket table from normal CDF; monotone by running max ----
        if (t < 257) {
            u32 dkb = (u32)t << 24;
            float d = depth_unkey(dkb);
            float u;
            if (d != d) u = (t < 128) ? 0.f : 1.f;
            else {
                float dc = fminf(fmaxf(d, -12.f), 12.f);
                u = 0.5f * erfcf(dc * 0.70710678f);
            }
            traw[t] = (u32)(u * (float)NBKT + 0.5f);
        }
        __syncthreads();
        if (t == 0) {
            u32 run = 0;
            for (int k = 0; k < 257; ++k) {
                u32 v = traw[k];
                if (v > NBKT) v = NBKT;
                if (v > run) run = v;
                Tg[k] = run;
            }
        }
    } else {
        // ---- ctab0: per-(hist-block,tile) u16 exclusive prefix ----
        int g = (b - 3) * 1024 + t;
        if (g < NTILES) {
            int w = g >> 1, sh = (g & 1) * 16;
            u32 run = 0;
            for (int s = 0; s < HB; ++s) {
                ctab0[s * NTILES + g] = (u16)run;
                run += (pcslc[s * PCW + w] >> sh) & 0xFFFFu;
            }
        }
    }
}

// Same block<->point mapping as hist; cursors = po + u16 ctab0 row in LDS.
// Writes 8B records in center-sorted order. LDS atomics only.
__global__ __launch_bounds__(HT) void point_scatter_kernel(const float2* __restrict__ pos,
                                                           const float* __restrict__ rad,
                                                           const float* __restrict__ depth,
                                                           const u16* __restrict__ ctab0,
                                                           const u32* __restrict__ po,
                                                           u64* __restrict__ pe) {
    __shared__ u32 cur[NTILES];
    int tid = threadIdx.x;
    for (int w = tid; w < NTILES; w += HT)
        cur[w] = po[w] + (u32)ctab0[blockIdx.x * NTILES + w];
    __syncthreads();
    for (int i = blockIdx.x * HT + tid; i < NPTS; i += HB * HT) {
        float2 p = pos[i];
        float r = rad[i];
        int x0, x1, y0, y1;
        tile_window(p.x, p.y, r, x0, x1, y0, y1);
        int cx = (int)(p.x * 0.0625f);
        int cy = (int)(p.y * 0.0625f);
        u32 dk = depth_key(depth[i]);
        u32 meta = ((u32)(cx - x0) << 11) | ((u32)(x1 - cx - 1) << 9)
                 | ((u32)y0 << 2) | (u32)(y1 - y0 - 1);
        u32 slot = atomicAdd(&cur[cx * NBH + cy], 1u);
        pe[slot] = ((u64)dk << 32) | ((u64)(u32)i << 13) | (u64)meta;
    }
}

// One block per tile: tail-fill slice + SINGLE coalesced candidate pass
// (append to LDS + bucket-hist fused), bucket scan, LDS->LDS scatter,
// per-thread insertion sort per bucket, coalesced write.  [R11-verified]
__global__ __launch_bounds__(256) void tile_build_kernel(const u32* __restrict__ po,
                                                         const u64* __restrict__ pe,
                                                         const u32* __restrict__ eo,
                                                         const u32* __restrict__ Tg,
                                                         float* __restrict__ out_idx,
                                                         float* __restrict__ out_depth) {
    __shared__ u64 keys[SORT_CAP];          // 8 KB  (append order)
    __shared__ u64 keys2[SORT_CAP];         // 8 KB  (bucketed order)
    __shared__ u32 boff[NBKT + 1];          // 2 KB
    __shared__ u32 bcur[NBKT];              // 2 KB
    __shared__ u32 Ts[257];
    __shared__ u32 wsum[4];
    __shared__ u32 lcnt;

    int tid = threadIdx.x;
    int lane = tid & 63;
    int wv = tid >> 6;

    // ---- fused tail fill: pad [total, EE) with -1 / 0 ----
    {
        u32 total = eo[NTILES];
        u32 tailn = EE - total;
        u32 per = (tailn + NTILES - 1) / NTILES;
        u64 s = (u64)total + (u64)blockIdx.x * per;
        u64 e = s + per; if (e > (u64)EE) e = EE;
        for (u64 i = s + tid; i < e; i += 256) {
            out_idx[i] = -1.f;
            out_depth[i] = 0.f;
        }
    }

    int t = tile_of_block(blockIdx.x);
    u32 base = eo[t];
    int cnt = (int)(eo[t + 1] - base);
    if (cnt <= 0) return;

    int tx = t / NBH;
    int ty = t % NBH;
    bool big = cnt > SORT_CAP;

    for (int b = tid; b < NBKT; b += 256) boff[b] = 0;
    for (int k = tid; k < 257; k += 256) Ts[k] = Tg[k];
    if (tid == 0) lcnt = 0;
    __syncthreads();

    int cx0 = tx - 2 < 0 ? 0 : tx - 2;
    int cx1 = tx + 2 > NBW - 1 ? NBW - 1 : tx + 2;
    int cy0 = ty - 2 < 0 ? 0 : ty - 2;
    int cy1 = ty + 2 > NBH - 1 ? NBH - 1 : ty + 2;

    if (!big) {
        // ---- single pass: append accepted keys to LDS + bucket histogram ----
        for (int cx = cx0; cx <= cx1; ++cx) {
            int dcx = cx - tx;                      // column-loop constant
            u32 s = po[cx * NBH + cy0];
            u32 e = po[cx * NBH + cy1 + 1];
            for (u32 i = s + tid; i < e; i += 256) {
                u64 v = pe[i];
                u32 meta = (u32)v & 0x1FFFu;
                int h = (int)(meta & 3u);
                int y0 = (int)((meta >> 2) & 127u);
                int dx1m1 = (int)((meta >> 9) & 3u);
                int dx0 = (int)((meta >> 11) & 3u);
                if (dx0 >= dcx && dx1m1 >= -dcx && ty >= y0 && ty <= y0 + h) {
                    u32 slot = atomicAdd(&lcnt, 1u);
                    keys[slot] = v;
                    atomicAdd(&boff[bucket_of((u32)(v >> 32), Ts)], 1u);
                }
            }
        }
        __syncthreads();

        // ---- exclusive scan of 512 buckets (2/thread + shfl scan) ----
        {
            int b0 = tid * 2;
            u32 h0 = boff[b0], h1 = boff[b0 + 1];
            u32 tsum = h0 + h1;
            u32 v = tsum;
            for (int off = 1; off < 64; off <<= 1) {
                u32 n = __shfl_up(v, off, 64);
                if (lane >= off) v += n;
            }
            if (lane == 63) wsum[wv] = v;
            __syncthreads();
            u32 wpre = 0;
            for (int w = 0; w < wv; ++w) wpre += wsum[w];
            u32 run = wpre + v - tsum;
            boff[b0] = run;     bcur[b0] = run;     run += h0;
            boff[b0 + 1] = run; bcur[b0 + 1] = run; run += h1;
            if (tid == 255) boff[NBKT] = run;
        }
        __syncthreads();

        // ---- LDS -> LDS scatter into bucketed order ----
        for (int i = tid; i < cnt; i += 256) {
            u64 v = keys[i];
            u32 slot = atomicAdd(&bcur[bucket_of((u32)(v >> 32), Ts)], 1u);
            keys2[slot] = v;
        }
        __syncthreads();

        // ---- per-thread insertion sort of each bucket (u64 = (dk,pid) order) ----
        for (int b = tid; b < NBKT; b += 256) {
            int s = (int)boff[b], e = (int)boff[b + 1];
            for (int i = s + 1; i < e; ++i) {
                u64 k = keys2[i];
                int j = i - 1;
                while (j >= s && keys2[j] > k) { keys2[j + 1] = keys2[j]; --j; }
                keys2[j + 1] = k;
            }
        }
        __syncthreads();

        // ---- decode + coalesced write ----
        for (int i = tid; i < cnt; i += 256) {
            u64 k = keys2[i];
            u32 pid = (u32)(k >> 13) & 0x7FFFFu;
            u32 dk  = (u32)(k >> 32);
            out_idx[base + i]   = (float)pid;
            out_depth[base + i] = depth_unkey(dk);
        }
    } else {
        // Statistically unreachable fallback: append to global, odd-even sort.
        for (int cx = cx0; cx <= cx1; ++cx) {
            int dcx = cx - tx;
            u32 s = po[cx * NBH + cy0];
            u32 e = po[cx * NBH + cy1 + 1];
            for (u32 i = s + tid; i < e; i += 256) {
                u64 v = pe[i];
                u32 meta = (u32)v & 0x1FFFu;
                int h = (int)(meta & 3u);
                int y0 = (int)((meta >> 2) & 127u);
                int dx1m1 = (int)((meta >> 9) & 3u);
                int dx0 = (int)((meta >> 11) & 3u);
                if (dx0 >= dcx && dx1m1 >= -dcx && ty >= y0 && ty <= y0 + h) {
                    u32 pid = (u32)(v >> 13) & 0x7FFFFu;
                    u32 dk  = (u32)(v >> 32);
                    u32 slot = atomicAdd(&lcnt, 1u);
                    out_idx[base + slot] = (float)pid;
                    out_depth[base + slot] = depth_unkey(dk);
                }
            }
        }
        __syncthreads();
        for (int round = 0; round < cnt; ++round) {
            for (int i = (round & 1) + 2 * tid; i + 1 < cnt; i += 512) {
                float fi0 = out_idx[base + i], fi1 = out_idx[base + i + 1];
                float fd0 = out_depth[base + i], fd1 = out_depth[base + i + 1];
                u64 k0 = ((u64)depth_key(fd0) << 19) | (u64)(u32)fi0;
                u64 k1 = ((u64)depth_key(fd1) << 19) | (u64)(u32)fi1;
                if (k0 > k1) {
                    out_idx[base + i] = fi1; out_idx[base + i + 1] = fi0;
                    out_depth[base + i] = fd1; out_depth[base + i + 1] = fd0;
                }
            }
            __syncthreads();
        }
    }
}

extern "C" void kernel_launch(void* const* d_in, const int* in_sizes, int n_in,
                              void* d_out, int out_size, void* d_ws, size_t ws_size,
                              hipStream_t stream) {
    (void)in_sizes; (void)n_in; (void)out_size; (void)ws_size;

    const float2* pos  = (const float2*)d_in[0];
    const float* rad   = (const float*)d_in[1];
    const float* depth = (const float*)d_in[2];

    float* out        = (float*)d_out;
    float* out_count  = out;                 // [NTILES]
    float* out_idx    = out + NTILES;        // [EE]
    float* out_depth  = out + NTILES + EE;   // [EE]

    // ws layout (~4.1 MB): 8B records first, then u32 arrays
    u64* pe     = (u64*)d_ws;                // [NPTS] packed records
    u32* po     = (u32*)(pe + NPTS);         // [NTILES+1]
    u32* eo     = po + NTILES + 1;           // [NTILES+1]
    u32* Tg     = eo + NTILES + 1;           // [257]

    // Large staging in the guaranteed-dead output tail (total entries <= 8M
    // of 12.5M since radius < 24 -> window <= 4x4). ctab0 u16 (1.0 MB) at end
    // of out_idx; pcslc (1.0 MB) + diffslc (1.1 MB, packed i16) at end of
    // out_depth. tile_build's fused tail-fill overwrites these afterwards.
    u16* ctab0   = (u16*)((u32*)out_idx + EE) - (size_t)HB * NTILES;
    u32* pcslc   = (u32*)(out_depth + EE) - ((size_t)HB * PCW + (size_t)HB * DCW);
    u32* diffslc = pcslc + (size_t)HB * PCW;

    hist_kernel<<<HB, HT, 0, stream>>>(pos, rad, pcslc, diffslc);
    scan_all_kernel<<<11, 1024, 0, stream>>>(pcslc, diffslc, po, eo,
                                             out_count, Tg, ctab0);
    point_scatter_kernel<<<HB, HT, 0, stream>>>(pos, rad, depth, ctab0, po, pe);
    tile_build_kernel<<<NTILES, 256, 0, stream>>>(po, pe, eo, Tg,
                                                  out_idx, out_depth);
}

// Round 14
// 185.691 us; speedup vs baseline: 1.2961x; 1.2961x over previous
//
#include <hip/hip_runtime.h>
#include <stdint.h>
#include <math.h>

typedef unsigned short u16;
typedef unsigned int u32;
typedef unsigned long long u64;

#define NBW 120
#define NBH 68
#define NTILES (NBW * NBH)       // 8160
#define NPTS 500000
#define EE 12500000              // N * K * K
#define SORT_CAP 768             // max tile count ~525 expected; global fallback guards
#define NBKT 512                 // distribution-sort buckets
#define HB 64                    // hist/scatter blocks
#define HT 1024                  // hist/scatter threads per block
#define DX 121                   // diff array x dim (0..120)
#define DY 69                    // diff array y dim (0..68)
#define DCELLS 8352              // 121*69 = 8349, padded even
#define DCW (DCELLS / 2)         // packed i16 words per slice
#define PCW 4080                 // 8160 cells / 2 per u16-packed word

__device__ __forceinline__ int clampi(int v, int lo, int hi) {
    return v < lo ? lo : (v > hi ? hi : v);
}

__device__ __forceinline__ void tile_window(float x, float y, float r,
                                            int& x0, int& x1, int& y0, int& y1) {
    x0 = clampi((int)floorf((x - r) * 0.0625f), 0, NBW);
    x1 = clampi((int)floorf((x + r) * 0.0625f) + 1, 0, NBW);
    y0 = clampi((int)floorf((y - r) * 0.0625f), 0, NBH);
    y1 = clampi((int)floorf((y + r) * 0.0625f) + 1, 0, NBH);
}

// monotone float -> u32 such that ascending u32 == DESCENDING float
__device__ __forceinline__ u32 depth_key(float d) {
    u32 fu = __float_as_uint(d);
    u32 asc = (fu & 0x80000000u) ? ~fu : (fu | 0x80000000u);
    return ~asc;
}
__device__ __forceinline__ float depth_unkey(u32 dk) {
    u32 asc = ~dk;
    u32 fu = (asc & 0x80000000u) ? (asc & 0x7FFFFFFFu) : ~asc;
    return __uint_as_float(fu);
}

__device__ __forceinline__ int tile_of_block(int b) {
    return (b & 7) * (NTILES / 8) + (b >> 3);
}

// Exactly monotone (in dk) bucket map: table lookup on top-8 bits + integer
// linear interpolation. T is monotone non-decreasing, 0..NBKT.
__device__ __forceinline__ u32 bucket_of(u32 dk, const u32* __restrict__ Ts) {
    u32 k = dk >> 24;
    u32 t0 = Ts[k], t1 = Ts[k + 1];
    u32 b = t0 + (((t1 - t0) * ((dk >> 8) & 0xFFFFu)) >> 16);
    return b >= NBKT ? (NBKT - 1) : b;
}

__device__ __forceinline__ void lds_inc16(u32* arr, int cell) {
    atomicAdd(&arr[cell >> 1], (cell & 1) ? 0x10000u : 1u);
}

// 8-byte record: [dk:32 | pid:19 | dx0:2 | dx1m1:2 | y0:7 | h:2]
// Full u64 compare sorts by (dk, pid). Window relative-x fits because
// radius < 24 => window within center±2 and span <= 4.

// 64 blocks x 1024: LDS point-count histogram (packed u16) and LDS 2D
// difference-array corners (packed u16, plus/minus split -> i16 slices).
__global__ __launch_bounds__(HT) void hist_kernel(const float2* __restrict__ pos,
                                                  const float* __restrict__ rad,
                                                  u32* __restrict__ pcslc,
                                                  u32* __restrict__ diffslc) {
    __shared__ u32 s_pc[PCW];
    __shared__ u32 s_dp[DCW];
    __shared__ u32 s_dm[DCW];
    int tid = threadIdx.x;
    for (int w = tid; w < PCW; w += HT) s_pc[w] = 0;
    for (int w = tid; w < DCW; w += HT) { s_dp[w] = 0; s_dm[w] = 0; }
    __syncthreads();

    for (int i = blockIdx.x * HT + tid; i < NPTS; i += HB * HT) {
        float2 p = pos[i];
        float r = rad[i];
        int x0, x1, y0, y1;
        tile_window(p.x, p.y, r, x0, x1, y0, y1);
        int cx = (int)(p.x * 0.0625f);
        int cy = (int)(p.y * 0.0625f);
        lds_inc16(s_pc, cx * NBH + cy);
        lds_inc16(s_dp, x0 * DY + y0);
        lds_inc16(s_dp, x1 * DY + y1);
        lds_inc16(s_dm, x0 * DY + y1);
        lds_inc16(s_dm, x1 * DY + y0);
    }
    __syncthreads();

    for (int w = tid; w < PCW; w += HT) pcslc[blockIdx.x * PCW + w] = s_pc[w];
    for (int wi = tid; wi < DCW; wi += HT) {
        u32 pw = s_dp[wi], mw = s_dm[wi];
        int d0 = (int)(pw & 0xFFFFu) - (int)(mw & 0xFFFFu);
        int d1 = (int)(pw >> 16)     - (int)(mw >> 16);
        diffslc[blockIdx.x * DCW + wi] = ((u32)d0 & 0xFFFFu) | ((u32)d1 << 16);
    }
}

// Fused reduce + cursor table (65 blocks — wide/shallow; R11-verified):
// per-tile totals (counts), per-(block,tile) u16 exclusive prefix (ctab0,
// WITHOUT po), and diff reduction (sdg).
__global__ void reduce_kernel(const u32* __restrict__ pcslc, const u32* __restrict__ diffslc,
                              u32* __restrict__ counts, u16* __restrict__ ctab0,
                              int* __restrict__ sdg) {
    int idx = blockIdx.x * 256 + threadIdx.x;
    if (idx < NTILES) {
        int sh = (idx & 1) * 16;
        int w = idx >> 1;
        u32 run = 0;
        for (int b = 0; b < HB; ++b) {
            ctab0[b * NTILES + idx] = (u16)run;
            run += (pcslc[b * PCW + w] >> sh) & 0xFFFFu;
        }
        counts[idx] = run;
    } else if (idx < NTILES + DCELLS) {
        int c = idx - NTILES;
        int wi = c >> 1, sh = (c & 1) * 16;
        int acc = 0;
        for (int b = 0; b < HB; ++b)
            acc += (int)(short)((diffslc[b * DCW + wi] >> sh) & 0xFFFFu);
        sdg[c] = acc;
    }
}

// 3 parallel blocks: 0 = point-count scan -> po; 1 = diff 2D prefix + entry
// scan -> eo + out_count; 2 = bucket table -> Tg.   [R11-verified]
__global__ __launch_bounds__(1024) void scan3_kernel(const u32* __restrict__ counts,
                                                     u32* __restrict__ po,
                                                     const int* __restrict__ sdg,
                                                     u32* __restrict__ eo,
                                                     float* __restrict__ out_count,
                                                     u32* __restrict__ Tg) {
    __shared__ u32 sA[1024], sB[1024];
    __shared__ int sd[DCELLS];
    __shared__ u32 traw[257];
    int t = threadIdx.x;
    int base = t * 8;

    if (blockIdx.x == 0) {
        // ---- point-count scan -> po ----
        u32 local[8]; u32 sum = 0;
#pragma unroll
        for (int j = 0; j < 8; ++j) {
            u32 c = (base + j < NTILES) ? counts[base + j] : 0u;
            local[j] = c; sum += c;
        }
        sA[t] = sum;
        __syncthreads();
        u32 *cur = sA, *nxt = sB;
        for (int off = 1; off < 1024; off <<= 1) {
            u32 v = cur[t];
            if (t >= off) v += cur[t - off];
            nxt[t] = v;
            __syncthreads();
            u32* tmp = cur; cur = nxt; nxt = tmp;
        }
        u32 run = cur[t] - sum;
#pragma unroll
        for (int j = 0; j < 8; ++j) {
            int idx = base + j;
            if (idx < NTILES) { po[idx] = run; run += local[j]; }
        }
        if (t == 1023) po[NTILES] = cur[1023];
    } else if (blockIdx.x == 1) {
        // ---- 2D prefix of diff array -> entry counts -> scan ----
        for (int c = t; c < DCELLS; c += 1024) sd[c] = sdg[c];
        __syncthreads();
        if (t < DX) { int run = 0; for (int y = 0; y < DY; ++y) { run += sd[t * DY + y]; sd[t * DY + y] = run; } }
        __syncthreads();
        if (t < DY) { int run = 0; for (int x = 0; x < DX; ++x) { run += sd[x * DY + t]; sd[x * DY + t] = run; } }
        __syncthreads();

        u32 local[8]; u32 sum = 0;
#pragma unroll
        for (int j = 0; j < 8; ++j) {
            int idx = base + j;
            u32 c = 0;
            if (idx < NTILES) {
                int x = idx / NBH, y = idx % NBH;
                c = (u32)sd[x * DY + y];
            }
            local[j] = c; sum += c;
        }
        sA[t] = sum;
        __syncthreads();
        u32 *cur = sA, *nxt = sB;
        for (int off = 1; off < 1024; off <<= 1) {
            u32 v = cur[t];
            if (t >= off) v += cur[t - off];
            nxt[t] = v;
            __syncthreads();
            u32* tmp = cur; cur = nxt; nxt = tmp;
        }
        u32 run = cur[t] - sum;
#pragma unroll
        for (int j = 0; j < 8; ++j) {
            int idx = base + j;
            if (idx < NTILES) {
                eo[idx] = run;
                out_count[idx] = (float)run;
                run += local[j];
            }
        }
        if (t == 1023) eo[NTILES] = cur[1023];
    } else {
        // ---- bucket table from normal CDF; monotone by running max ----
        if (t < 257) {
            u32 dkb = (u32)t << 24;
            float d = depth_unkey(dkb);
            float u;
            if (d != d) u = (t < 128) ? 0.f : 1.f;
            else {
                float dc = fminf(fmaxf(d, -12.f), 12.f);
                u = 0.5f * erfcf(dc * 0.70710678f);
            }
            traw[t] = (u32)(u * (float)NBKT + 0.5f);
        }
        __syncthreads();
        if (t == 0) {
            u32 run = 0;
            for (int k = 0; k < 257; ++k) {
                u32 v = traw[k];
                if (v > NBKT) v = NBKT;
                if (v > run) run = v;
                Tg[k] = run;
            }
        }
    }
}

// Same block<->point mapping as hist; cursors = po + u16 ctab0 row in LDS.
// Writes 8B records in center-sorted order. LDS atomics only.  [R11-verified]
__global__ __launch_bounds__(HT) void point_scatter_kernel(const float2* __restrict__ pos,
                                                           const float* __restrict__ rad,
                                                           const float* __restrict__ depth,
                                                           const u16* __restrict__ ctab0,
                                                           const u32* __restrict__ po,
                                                           u64* __restrict__ pe) {
    __shared__ u32 cur[NTILES];
    int tid = threadIdx.x;
    for (int w = tid; w < NTILES; w += HT)
        cur[w] = po[w] + (u32)ctab0[blockIdx.x * NTILES + w];
    __syncthreads();
    for (int i = blockIdx.x * HT + tid; i < NPTS; i += HB * HT) {
        float2 p = pos[i];
        float r = rad[i];
        int x0, x1, y0, y1;
        tile_window(p.x, p.y, r, x0, x1, y0, y1);
        int cx = (int)(p.x * 0.0625f);
        int cy = (int)(p.y * 0.0625f);
        u32 dk = depth_key(depth[i]);
        u32 meta = ((u32)(cx - x0) << 11) | ((u32)(x1 - cx - 1) << 9)
                 | ((u32)y0 << 2) | (u32)(y1 - y0 - 1);
        u32 slot = atomicAdd(&cur[cx * NBH + cy], 1u);
        pe[slot] = ((u64)dk << 32) | ((u64)(u32)i << 13) | (u64)meta;
    }
}

// One block per tile: tail-fill slice + SINGLE coalesced candidate pass
// (append to LDS + bucket-hist fused), bucket scan, LDS->LDS scatter,
// per-thread insertion sort per bucket, coalesced write.
// [R11-verified; SORT_CAP=768 -> LDS ~17.4 KB -> 8 blocks/CU]
__global__ __launch_bounds__(256) void tile_build_kernel(const u32* __restrict__ po,
                                                         const u64* __restrict__ pe,
                                                         const u32* __restrict__ eo,
                                                         const u32* __restrict__ Tg,
                                                         float* __restrict__ out_idx,
                                                         float* __restrict__ out_depth) {
    __shared__ u64 keys[SORT_CAP];          // 6 KB  (append order)
    __shared__ u64 keys2[SORT_CAP];         // 6 KB  (bucketed order)
    __shared__ u32 boff[NBKT + 1];          // 2 KB
    __shared__ u32 bcur[NBKT];              // 2 KB
    __shared__ u32 Ts[257];
    __shared__ u32 wsum[4];
    __shared__ u32 lcnt;

    int tid = threadIdx.x;
    int lane = tid & 63;
    int wv = tid >> 6;

    // ---- fused tail fill: pad [total, EE) with -1 / 0 ----
    {
        u32 total = eo[NTILES];
        u32 tailn = EE - total;
        u32 per = (tailn + NTILES - 1) / NTILES;
        u64 s = (u64)total + (u64)blockIdx.x * per;
        u64 e = s + per; if (e > (u64)EE) e = EE;
        for (u64 i = s + tid; i < e; i += 256) {
            out_idx[i] = -1.f;
            out_depth[i] = 0.f;
        }
    }

    int t = tile_of_block(blockIdx.x);
    u32 base = eo[t];
    int cnt = (int)(eo[t + 1] - base);
    if (cnt <= 0) return;

    int tx = t / NBH;
    int ty = t % NBH;
    bool big = cnt > SORT_CAP;

    for (int b = tid; b < NBKT; b += 256) boff[b] = 0;
    for (int k = tid; k < 257; k += 256) Ts[k] = Tg[k];
    if (tid == 0) lcnt = 0;
    __syncthreads();

    int cx0 = tx - 2 < 0 ? 0 : tx - 2;
    int cx1 = tx + 2 > NBW - 1 ? NBW - 1 : tx + 2;
    int cy0 = ty - 2 < 0 ? 0 : ty - 2;
    int cy1 = ty + 2 > NBH - 1 ? NBH - 1 : ty + 2;

    if (!big) {
        // ---- single pass: append accepted keys to LDS + bucket histogram ----
        for (int cx = cx0; cx <= cx1; ++cx) {
            int dcx = cx - tx;                      // column-loop constant
            u32 s = po[cx * NBH + cy0];
            u32 e = po[cx * NBH + cy1 + 1];
            for (u32 i = s + tid; i < e; i += 256) {
                u64 v = pe[i];
                u32 meta = (u32)v & 0x1FFFu;
                int h = (int)(meta & 3u);
                int y0 = (int)((meta >> 2) & 127u);
                int dx1m1 = (int)((meta >> 9) & 3u);
                int dx0 = (int)((meta >> 11) & 3u);
                if (dx0 >= dcx && dx1m1 >= -dcx && ty >= y0 && ty <= y0 + h) {
                    u32 slot = atomicAdd(&lcnt, 1u);
                    keys[slot] = v;
                    atomicAdd(&boff[bucket_of((u32)(v >> 32), Ts)], 1u);
                }
            }
        }
        __syncthreads();

        // ---- exclusive scan of 512 buckets (2/thread + shfl scan) ----
        {
            int b0 = tid * 2;
            u32 h0 = boff[b0], h1 = boff[b0 + 1];
            u32 tsum = h0 + h1;
            u32 v = tsum;
            for (int off = 1; off < 64; off <<= 1) {
                u32 n = __shfl_up(v, off, 64);
                if (lane >= off) v += n;
            }
            if (lane == 63) wsum[wv] = v;
            __syncthreads();
            u32 wpre = 0;
            for (int w = 0; w < wv; ++w) wpre += wsum[w];
            u32 run = wpre + v - tsum;
            boff[b0] = run;     bcur[b0] = run;     run += h0;
            boff[b0 + 1] = run; bcur[b0 + 1] = run; run += h1;
            if (tid == 255) boff[NBKT] = run;
        }
        __syncthreads();

        // ---- LDS -> LDS scatter into bucketed order ----
        for (int i = tid; i < cnt; i += 256) {
            u64 v = keys[i];
            u32 slot = atomicAdd(&bcur[bucket_of((u32)(v >> 32), Ts)], 1u);
            keys2[slot] = v;
        }
        __syncthreads();

        // ---- per-thread insertion sort of each bucket (u64 = (dk,pid) order) ----
        for (int b = tid; b < NBKT; b += 256) {
            int s = (int)boff[b], e = (int)boff[b + 1];
            for (int i = s + 1; i < e; ++i) {
                u64 k = keys2[i];
                int j = i - 1;
                while (j >= s && keys2[j] > k) { keys2[j + 1] = keys2[j]; --j; }
                keys2[j + 1] = k;
            }
        }
        __syncthreads();

        // ---- decode + coalesced write ----
        for (int i = tid; i < cnt; i += 256) {
            u64 k = keys2[i];
            u32 pid = (u32)(k >> 13) & 0x7FFFFu;
            u32 dk  = (u32)(k >> 32);
            out_idx[base + i]   = (float)pid;
            out_depth[base + i] = depth_unkey(dk);
        }
    } else {
        // Statistically unreachable fallback: append to global, odd-even sort.
        for (int cx = cx0; cx <= cx1; ++cx) {
            int dcx = cx - tx;
            u32 s = po[cx * NBH + cy0];
            u32 e = po[cx * NBH + cy1 + 1];
            for (u32 i = s + tid; i < e; i += 256) {
                u64 v = pe[i];
                u32 meta = (u32)v & 0x1FFFu;
                int h = (int)(meta & 3u);
                int y0 = (int)((meta >> 2) & 127u);
                int dx1m1 = (int)((meta >> 9) & 3u);
                int dx0 = (int)((meta >> 11) & 3u);
                if (dx0 >= dcx && dx1m1 >= -dcx && ty >= y0 && ty <= y0 + h) {
                    u32 pid = (u32)(v >> 13) & 0x7FFFFu;
                    u32 dk  = (u32)(v >> 32);
                    u32 slot = atomicAdd(&lcnt, 1u);
                    out_idx[base + slot] = (float)pid;
                    out_depth[base + slot] = depth_unkey(dk);
                }
            }
        }
        __syncthreads();
        for (int round = 0; round < cnt; ++round) {
            for (int i = (round & 1) + 2 * tid; i + 1 < cnt; i += 512) {
                float fi0 = out_idx[base + i], fi1 = out_idx[base + i + 1];
                float fd0 = out_depth[base + i], fd1 = out_depth[base + i + 1];
                u64 k0 = ((u64)depth_key(fd0) << 19) | (u64)(u32)fi0;
                u64 k1 = ((u64)depth_key(fd1) << 19) | (u64)(u32)fi1;
                if (k0 > k1) {
                    out_idx[base + i] = fi1; out_idx[base + i + 1] = fi0;
                    out_depth[base + i] = fd1; out_depth[base + i + 1] = fd0;
                }
            }
            __syncthreads();
        }
    }
}

extern "C" void kernel_launch(void* const* d_in, const int* in_sizes, int n_in,
                              void* d_out, int out_size, void* d_ws, size_t ws_size,
                              hipStream_t stream) {
    (void)in_sizes; (void)n_in; (void)out_size; (void)ws_size;

    const float2* pos  = (const float2*)d_in[0];
    const float* rad   = (const float*)d_in[1];
    const float* depth = (const float*)d_in[2];

    float* out        = (float*)d_out;
    float* out_count  = out;                 // [NTILES]
    float* out_idx    = out + NTILES;        // [EE]
    float* out_depth  = out + NTILES + EE;   // [EE]

    // ws layout (~4.1 MB): 8B records first, then u32 arrays
    u64* pe     = (u64*)d_ws;                // [NPTS] packed records
    u32* counts = (u32*)(pe + NPTS);         // [NTILES]
    u32* po     = counts + NTILES;           // [NTILES+1]
    u32* eo     = po + NTILES + 1;           // [NTILES+1]
    int* sdg    = (int*)(eo + NTILES + 1);   // [DCELLS]
    u32* Tg     = (u32*)(sdg + DCELLS);      // [257]

    // Large staging in the guaranteed-dead output tail (total entries <= 8M
    // of 12.5M since radius < 24 -> window <= 4x4). ctab0 u16 (1.0 MB) at end
    // of out_idx; pcslc (1.0 MB) + diffslc (1.1 MB, packed i16) at end of
    // out_depth. tile_build's fused tail-fill overwrites these afterwards.
    u16* ctab0   = (u16*)((u32*)out_idx + EE) - (size_t)HB * NTILES;
    u32* pcslc   = (u32*)(out_depth + EE) - ((size_t)HB * PCW + (size_t)HB * DCW);
    u32* diffslc = pcslc + (size_t)HB * PCW;

    hist_kernel<<<HB, HT, 0, stream>>>(pos, rad, pcslc, diffslc);
    reduce_kernel<<<(NTILES + DCELLS + 255) / 256, 256, 0, stream>>>(pcslc, diffslc,
                                                                     counts, ctab0, sdg);
    scan3_kernel<<<3, 1024, 0, stream>>>(counts, po, sdg, eo, out_count, Tg);
    point_scatter_kernel<<<HB, HT, 0, stream>>>(pos, rad, depth, ctab0, po, pe);
    tile_build_kernel<<<NTILES, 256, 0, stream>>>(po, pe, eo, Tg,
                                                  out_idx, out_depth);
}